// Round 10
// baseline (261.086 us; speedup 1.0000x reference)
//
#include <hip/hip_runtime.h>
#include <hip/hip_cooperative_groups.h>

namespace cg = cooperative_groups;

// RFCN PSROI — single cooperative kernel:
//   out[b,n,g] = B'[g] + (1/denom) * sum_{bin} Z[b,g,h,w]
//   Z = einsum('bchw,gc->bghw', features, W'),  W'[g,c] = sum_k w[g*9+k, c]
// Phase 0: distributed weight fold -> Wred/Bred (workspace)
// Phase 1: projection -> 25-ch partial score maps (2 channel-chunks;
//          16 waves/block each owning 32 channels, LDS 16->1 reduce)
// Phase 2: blocks 0..49: sum 2 chunks + 2D prefix scan in LDS +
//          per-proposal 4-corner gather.
// grid.sync() between phases replaces kernel-launch gaps.

#define HW 4096      // 64*64
#define NG 25        // 21 cls + 4 reg groups
#define CIN 1024
#define B 2
#define NPROP 1000
#define NCH 2                 // channel chunks in workspace
#define CK (CIN / NCH)        // 512 channels per chunk
#define NSL 16                // wave slices per proj block
#define CS (CK / NSL)         // 32 channels per wave
#define MHW (B * NG * HW)     // 204800: one partial chunk

__global__ __launch_bounds__(1024)
void rfcn_fused(const float* __restrict__ feats,
                const float* __restrict__ w_cls,
                const float* __restrict__ b_cls,
                const float* __restrict__ w_reg,
                const float* __restrict__ b_reg,
                const int* __restrict__ props,
                float* __restrict__ Wred,   // [25][1024] ws
                float* __restrict__ Bred,   // [25] ws
                float* __restrict__ part,   // [2][2][25][4096] ws
                float* __restrict__ out) {
    const int t = threadIdx.x;
    const int bid = blockIdx.x;           // 0..255
    __shared__ float red[NSL * NG * 64];  // 100 KB; reused as scan tile in ph2

    // ---------------- phase 0: weight fold (distributed) ----------------
    {
        const int i = bid * 1024 + t;
        if (i < NG * CIN) {
            const int g = i >> 10, c = i & (CIN - 1);
            float s = 0.f;
            if (g < 21) {
                #pragma unroll
                for (int k = 0; k < 9; ++k) s += w_cls[(size_t)(g * 9 + k) * CIN + c];
            } else {
                const int gr = g - 21;
                #pragma unroll
                for (int k = 0; k < 9; ++k) s += w_reg[(size_t)(gr * 9 + k) * CIN + c];
            }
            Wred[i] = s;
        } else if (i < NG * CIN + NG) {
            const int g = i - NG * CIN;
            float s = 0.f;
            if (g < 21) {
                #pragma unroll
                for (int k = 0; k < 9; ++k) s += b_cls[g * 9 + k];
            } else {
                #pragma unroll
                for (int k = 0; k < 9; ++k) s += b_reg[(g - 21) * 9 + k];
            }
            Bred[g] = s;
        }
    }
    __threadfence();            // cross-XCD: write back L2 before handoff
    cg::this_grid().sync();

    // ---------------- phase 1: projection ----------------
    {
        const int p = t & 63;                      // pixel within tile
        // wave id in SGPR keeps weight loads scalar (s_load broadcast)
        const int sl = __builtin_amdgcn_readfirstlane(t >> 6);   // 0..15
        const int px_tile = bid & 63;
        const int chunk = (bid >> 6) & 1;
        const int b = bid >> 7;
        const int pix0 = px_tile * 64;
        const int c0 = chunk * CK + sl * CS;       // wave's first channel

        const float* __restrict__ f = feats + ((size_t)b * CIN + c0) * HW + pix0 + p;
        const float* __restrict__ wgt = Wred + c0; // scalar-indexed

        float acc[NG];
        #pragma unroll
        for (int g = 0; g < NG; ++g) acc[g] = 0.f;

        #pragma unroll
        for (int cc = 0; cc < CS; cc += 16) {
            float fv[16];
            #pragma unroll
            for (int j = 0; j < 16; ++j) fv[j] = f[(size_t)(cc + j) * HW];
            #pragma unroll
            for (int j = 0; j < 16; ++j)
                #pragma unroll
                for (int g = 0; g < NG; ++g)
                    acc[g] += fv[j] * wgt[g * CIN + cc + j];
        }

        // LDS 16-wave reduction: red[slice][g][p]
        #pragma unroll
        for (int g = 0; g < NG; ++g) red[(sl * NG + g) * 64 + p] = acc[g];
        __syncthreads();

        float* __restrict__ o = part + ((size_t)(chunk * B + b) * NG) * HW + pix0;
        for (int idx = t; idx < NG * 64; idx += 1024) {
            const int g = idx >> 6, pp = idx & 63;
            float s = 0.f;
            #pragma unroll
            for (int ss = 0; ss < NSL; ++ss) s += red[(ss * NG + g) * 64 + pp];
            o[(size_t)g * HW + pp] = s;
        }
    }
    __threadfence();            // cross-XCD: write back L2 before handoff
    cg::this_grid().sync();

    // ---------------- phase 2: integral + gather (blocks 0..49) ----------
    if (bid < B * NG) {
        float* tile = red;               // alias: needs 64*65*4 = 16.6 KB
        const int m = bid;               // b*25 + g
        const int lane = t & 63;
        const int wave = t >> 6;         // 0..15
        const int b = m / NG;
        const int g = m - b * NG;        // block-uniform
        __syncthreads();                 // red's phase-1 lifetime ended

        // 2-chunk sum into tile (padded 65-stride)
        #pragma unroll
        for (int i = 0; i < 4; ++i) {
            const int idx = i * 1024 + t;
            const float v = part[(size_t)m * HW + idx]
                          + part[(size_t)(B * NG + m) * HW + idx];
            tile[(idx >> 6) * 65 + (idx & 63)] = v;
        }
        __syncthreads();

        // row scans — wave w owns rows [w*4, w*4+4), lane = column
        #pragma unroll
        for (int i = 0; i < 4; ++i) {
            const int row = wave * 4 + i;
            float v = tile[row * 65 + lane];
            #pragma unroll
            for (int d = 1; d < 64; d <<= 1) {
                float u = __shfl_up(v, (unsigned)d, 64);
                if (lane >= d) v += u;
            }
            tile[row * 65 + lane] = v;
        }
        __syncthreads();

        // column scans — wave w owns cols [w*4, w*4+4), lane = row
        #pragma unroll
        for (int i = 0; i < 4; ++i) {
            const int col = wave * 4 + i;
            float v = tile[lane * 65 + col];
            #pragma unroll
            for (int d = 1; d < 64; d <<= 1) {
                float u = __shfl_up(v, (unsigned)d, 64);
                if (lane >= d) v += u;
            }
            tile[lane * 65 + col] = v;
        }
        __syncthreads();

        // per-proposal 4-corner lookups straight from LDS
        const float bias = Bred[g];
        const int n = t;
        if (n < NPROP) {
            const int4 pr = ((const int4*)props)[b * NPROP + n];
            const int x1 = pr.x >> 5;            // floor(px/32), px >= 0
            const int y1 = pr.y >> 5;
            const int x2 = (pr.z + 31) >> 5;     // ceil
            const int y2 = (pr.w + 31) >> 5;
            const int wb = (x2 - x1 + 2) / 3;    // ceil((x2-x1)/3), >= 1
            const int hb = (y2 - y1 + 2) / 3;
            const int c2 = x1 + wb - 1;          // inclusive corner, <= 63
            const int r2 = y1 + hb - 1;

            float s = tile[r2 * 65 + c2];
            if (x1 > 0)           s -= tile[r2 * 65 + (x1 - 1)];
            if (y1 > 0)           s -= tile[(y1 - 1) * 65 + c2];
            if (x1 > 0 && y1 > 0) s += tile[(y1 - 1) * 65 + (x1 - 1)];
            const float v = bias + s / (float)(hb * wb);
            if (g < 21)  // block-uniform branch
                out[(size_t)(b * NPROP + n) * 21 + g] = v;
            else
                out[(size_t)(B * NPROP * 21) + (size_t)(b * NPROP + n) * 4 + (g - 21)] = v;
        }
    }
}

extern "C" void kernel_launch(void* const* d_in, const int* in_sizes, int n_in,
                              void* d_out, int out_size, void* d_ws, size_t ws_size,
                              hipStream_t stream) {
    const float* feats = (const float*)d_in[0];  // [2,1024,64,64]
    const float* w_cls = (const float*)d_in[1];  // [189,1024]
    const float* b_cls = (const float*)d_in[2];  // [189]
    const float* w_reg = (const float*)d_in[3];  // [36,1024]
    const float* b_reg = (const float*)d_in[4];  // [36]
    const int*   props = (const int*)d_in[5];    // [2,1000,4]
    float* out = (float*)d_out;
    float* ws  = (float*)d_ws;

    // workspace layout (floats): ~1.8 MB total
    float* Wred = ws;                        // 25600
    float* Bred = ws + 25600;                // 25 (next region 128B-aligned)
    float* part = ws + 25632;                // 2 * 204800

    void* args[] = {(void*)&feats, (void*)&w_cls, (void*)&b_cls, (void*)&w_reg,
                    (void*)&b_reg, (void*)&props, (void*)&Wred, (void*)&Bred,
                    (void*)&part, (void*)&out};
    hipLaunchCooperativeKernel((const void*)rfcn_fused, dim3(256), dim3(1024),
                               args, 0, stream);
}

// Round 11
// 28.416 us; speedup vs baseline: 9.1879x; 9.1879x over previous
//
#include <hip/hip_runtime.h>

// RFCN PSROI — algebraic restructure (3 launches, round-9 skeleton):
//   out[b,n,g] = B'[g] + (1/denom) * sum_{bin} Z[b,g,h,w]
//   Z = einsum('bchw,gc->bghw', features, W'),  W'[g,c] = sum_k w[g*9+k, c]
// (1) fold weights, (2) project features -> 25-ch partial maps (4 channel
// chunks; 128-pixel float2 tiles; 16 waves each owning 16 channels; paired-
// wave LDS reduce), (3) per (b,g): sum 4 chunks + 2D prefix scan + gather.

#define HW 4096      // 64*64
#define NG 25        // 21 cls + 4 reg groups
#define CIN 1024
#define B 2
#define NPROP 1000
#define NCH 4                 // channel chunks in workspace
#define CK (CIN / NCH)        // 256 channels per chunk
#define NSL 16                // wave slices per proj block
#define CS (CK / NSL)         // 16 channels per wave
#define MHW (B * NG * HW)     // 204800: one partial chunk
#define PX 128                // pixels per proj block (64 float2)

// ---------------- Kernel 1: fold weights over the K*K=9 channel groups ----
__global__ void rfcn_wfold(const float* __restrict__ w_cls,
                           const float* __restrict__ b_cls,
                           const float* __restrict__ w_reg,
                           const float* __restrict__ b_reg,
                           float* __restrict__ Wred,   // [25][1024]
                           float* __restrict__ Bred) { // [25]
    int i = blockIdx.x * 256 + threadIdx.x;
    if (i < NG * CIN) {
        int g = i >> 10, c = i & (CIN - 1);
        float s = 0.f;
        if (g < 21) {
            #pragma unroll
            for (int k = 0; k < 9; ++k) s += w_cls[(size_t)(g * 9 + k) * CIN + c];
        } else {
            int gr = g - 21;
            #pragma unroll
            for (int k = 0; k < 9; ++k) s += w_reg[(size_t)(gr * 9 + k) * CIN + c];
        }
        Wred[i] = s;
    } else if (i < NG * CIN + NG) {
        int g = i - NG * CIN;
        float s = 0.f;
        if (g < 21) {
            #pragma unroll
            for (int k = 0; k < 9; ++k) s += b_cls[g * 9 + k];
        } else {
            #pragma unroll
            for (int k = 0; k < 9; ++k) s += b_reg[(g - 21) * 9 + k];
        }
        Bred[g] = s;
    }
}

// ---------------- Kernel 2: projection  Z_partial = W' x F ----------------
// grid = (32 px tiles, 4 chunks, B) = 256 blocks, block = 1024 (16 waves).
// Wave sl owns channels [chunk*256 + sl*16, +16); lane l owns pixel pair
// {pix0+2l, pix0+2l+1} (float2 loads, v_pk_fma-able FMAs).
// part layout: [chunk][b][g][4096]
__global__ __launch_bounds__(1024)
void rfcn_proj(const float* __restrict__ feats,
               const float* __restrict__ Wred,
               float* __restrict__ part) {
    const int t = threadIdx.x;
    const int l = t & 63;                      // lane = float2 pixel pair
    // wave id in SGPR keeps weight loads scalar (s_load broadcast)
    const int sl = __builtin_amdgcn_readfirstlane(t >> 6);   // 0..15
    const int pix0 = blockIdx.x * PX;
    const int chunk = blockIdx.y;
    const int b = blockIdx.z;
    const int c0 = chunk * CK + sl * CS;       // wave's first channel

    const float2* __restrict__ f2 =
        (const float2*)feats + (size_t)(b * CIN + c0) * (HW / 2) + (pix0 >> 1) + l;
    const float* __restrict__ wgt = Wred + c0; // scalar-indexed -> s_load

    float2 acc[NG];
    #pragma unroll
    for (int g = 0; g < NG; ++g) acc[g] = make_float2(0.f, 0.f);

    // all 16 channel loads independent and in flight, then packed FMAs
    float2 fv[CS];
    #pragma unroll
    for (int j = 0; j < CS; ++j) fv[j] = f2[(size_t)j * (HW / 2)];
    #pragma unroll
    for (int j = 0; j < CS; ++j)
        #pragma unroll
        for (int g = 0; g < NG; ++g) {
            const float w = wgt[g * CIN + j];
            acc[g].x += fv[j].x * w;
            acc[g].y += fv[j].y * w;
        }

    // paired-wave LDS reduction: red2[8 slices][25 g][64 px-pairs] (102.4 KB)
    __shared__ float2 red2[8 * NG * 64];
    if (sl >= 8) {
        #pragma unroll
        for (int g = 0; g < NG; ++g) red2[((sl - 8) * NG + g) * 64 + l] = acc[g];
    }
    __syncthreads();
    if (sl < 8) {
        #pragma unroll
        for (int g = 0; g < NG; ++g) {
            float2 r = red2[(sl * NG + g) * 64 + l];
            r.x += acc[g].x; r.y += acc[g].y;
            red2[(sl * NG + g) * 64 + l] = r;
        }
    }
    __syncthreads();

    // 8->1 sum + coalesced float2 store
    float2* __restrict__ o2 =
        (float2*)part + (size_t)(chunk * B + b) * NG * (HW / 2) + (pix0 >> 1);
    for (int idx = t; idx < NG * 64; idx += 1024) {
        const int g = idx >> 6, l2 = idx & 63;
        float2 s = make_float2(0.f, 0.f);
        #pragma unroll
        for (int ss = 0; ss < 8; ++ss) {
            const float2 r = red2[(ss * NG + g) * 64 + l2];
            s.x += r.x; s.y += r.y;
        }
        o2[(size_t)g * (HW / 2) + l2] = s;
    }
}

// ---------------- Kernel 3: 4-chunk sum + 2D prefix sum + gather -----------
// grid = 50 (m = b*25+g), block = 1024 (16 waves) — each wave scans 4 rows
// then 4 cols (independent 6-deep shfl chains).
// LDS 64x65: row phase conflict-free via pad; col phase stride 65 == 1
// (mod 32) -> distinct banks per lane.
__global__ __launch_bounds__(1024)
void rfcn_integral_gather(const float* __restrict__ part,
                          const int* __restrict__ props,
                          const float* __restrict__ Bred,
                          float* __restrict__ out) {
    const int m = blockIdx.x;        // b*25 + g
    const int t = threadIdx.x;
    const int lane = t & 63;
    const int wave = t >> 6;         // 0..15
    const int b = m / NG;
    const int g = m - b * NG;        // block-uniform
    __shared__ float tile[64 * 65];

    // phase 1: sum the 4 partial chunks (8 independent float2 loads/thread)
    const float2* __restrict__ p2 = (const float2*)part + (size_t)m * (HW / 2);
    #pragma unroll
    for (int i = 0; i < 2; ++i) {
        const int idx = i * 1024 + t;            // float2 index in [0,2048)
        float2 v[NCH];
        #pragma unroll
        for (int ch = 0; ch < NCH; ++ch)
            v[ch] = p2[(size_t)ch * (MHW / 2) + idx];
        float2 s = make_float2(0.f, 0.f);
        #pragma unroll
        for (int ch = 0; ch < NCH; ++ch) { s.x += v[ch].x; s.y += v[ch].y; }
        const int row = idx >> 5;                // (2*idx)/64
        const int col = (idx & 31) * 2;
        tile[row * 65 + col]     = s.x;
        tile[row * 65 + col + 1] = s.y;
    }
    __syncthreads();

    // phase 2: row scans — wave w owns rows [w*4, w*4+4), lane = column
    #pragma unroll
    for (int i = 0; i < 4; ++i) {
        const int row = wave * 4 + i;
        float v = tile[row * 65 + lane];
        #pragma unroll
        for (int d = 1; d < 64; d <<= 1) {
            float u = __shfl_up(v, (unsigned)d, 64);
            if (lane >= d) v += u;
        }
        tile[row * 65 + lane] = v;
    }
    __syncthreads();

    // phase 3: column scans — wave w owns cols [w*4, w*4+4), lane = row
    #pragma unroll
    for (int i = 0; i < 4; ++i) {
        const int col = wave * 4 + i;
        float v = tile[lane * 65 + col];
        #pragma unroll
        for (int d = 1; d < 64; d <<= 1) {
            float u = __shfl_up(v, (unsigned)d, 64);
            if (lane >= d) v += u;
        }
        tile[lane * 65 + col] = v;
    }
    __syncthreads();

    // phase 4: per-proposal 4-corner lookups straight from LDS
    const float bias = Bred[g];
    const int n = t;
    if (n < NPROP) {
        const int4 pr = ((const int4*)props)[b * NPROP + n];
        const int x1 = pr.x >> 5;            // floor(px/32), px >= 0
        const int y1 = pr.y >> 5;
        const int x2 = (pr.z + 31) >> 5;     // ceil
        const int y2 = (pr.w + 31) >> 5;
        const int wb = (x2 - x1 + 2) / 3;    // ceil((x2-x1)/3), >= 1
        const int hb = (y2 - y1 + 2) / 3;
        const int c2 = x1 + wb - 1;          // inclusive corner, <= 63
        const int r2 = y1 + hb - 1;

        float s = tile[r2 * 65 + c2];
        if (x1 > 0)           s -= tile[r2 * 65 + (x1 - 1)];
        if (y1 > 0)           s -= tile[(y1 - 1) * 65 + c2];
        if (x1 > 0 && y1 > 0) s += tile[(y1 - 1) * 65 + (x1 - 1)];
        const float v = bias + s / (float)(hb * wb);
        if (g < 21)  // block-uniform branch
            out[(size_t)(b * NPROP + n) * 21 + g] = v;
        else
            out[(size_t)(B * NPROP * 21) + (size_t)(b * NPROP + n) * 4 + (g - 21)] = v;
    }
}

extern "C" void kernel_launch(void* const* d_in, const int* in_sizes, int n_in,
                              void* d_out, int out_size, void* d_ws, size_t ws_size,
                              hipStream_t stream) {
    const float* feats = (const float*)d_in[0];  // [2,1024,64,64]
    const float* w_cls = (const float*)d_in[1];  // [189,1024]
    const float* b_cls = (const float*)d_in[2];  // [189]
    const float* w_reg = (const float*)d_in[3];  // [36,1024]
    const float* b_reg = (const float*)d_in[4];  // [36]
    const int*   props = (const int*)d_in[5];    // [2,1000,4]
    float* out = (float*)d_out;
    float* ws  = (float*)d_ws;

    // workspace layout (floats): ~3.4 MB total
    float* Wred = ws;                        // 25600
    float* Bred = ws + 25600;                // 25 (next region 128B-aligned)
    float* part = ws + 25632;                // 4 * 204800

    rfcn_wfold<<<(NG * CIN + NG + 255) / 256, 256, 0, stream>>>(
        w_cls, b_cls, w_reg, b_reg, Wred, Bred);
    rfcn_proj<<<dim3(HW / PX, NCH, B), 1024, 0, stream>>>(feats, Wred, part);
    rfcn_integral_gather<<<B * NG, 1024, 0, stream>>>(part, props, Bred, out);
}